// Round 15
// baseline (72.719 us; speedup 1.0000x reference)
//
#include <hip/hip_runtime.h>
#include <hip/hip_bf16.h>
#include <stdint.h>

typedef __attribute__((ext_vector_type(8))) __bf16 bf16x8;
typedef __attribute__((ext_vector_type(4))) float f32x4;
typedef __attribute__((ext_vector_type(16))) float f32x16;
typedef __attribute__((ext_vector_type(8))) unsigned short u16x8;

__device__ __forceinline__ unsigned short f2bf(float f) {
    unsigned u = __builtin_bit_cast(unsigned, f);
    return (unsigned short)((u + 0x7fffu + ((u >> 16) & 1u)) >> 16);  // RNE
}

__device__ __forceinline__ void glds16(const void* g, void* l) {
    __builtin_amdgcn_global_load_lds(
        (const __attribute__((address_space(1))) unsigned int*)(uintptr_t)g,
        (__attribute__((address_space(3))) unsigned int*)l, 16, 0, 0);
}

#define VMCNT(n) asm volatile("s_waitcnt vmcnt(" #n ")" ::: "memory")
#define BAR()                                  \
    do {                                       \
        asm volatile("" ::: "memory");         \
        __builtin_amdgcn_s_barrier();          \
        asm volatile("" ::: "memory");         \
    } while (0)
// Read-completion fence: s_barrier does NOT drain lgkmcnt, and hipcc may sink
// register-only MFMAs (and their implicit lgkm waits) past an asm barrier
// (rule 18).  Before any barrier that permits buffer overwrite, force all
// outstanding LDS reads to complete and pin the schedule.
#define LGKM0()                                            \
    do {                                                   \
        asm volatile("s_waitcnt lgkmcnt(0)" ::: "memory"); \
        __builtin_amdgcn_sched_barrier(0);                 \
    } while (0)

#define MFMA16(a, b, c) __builtin_amdgcn_mfma_f32_16x16x32_bf16((a), (b), (c), 0, 0, 0)
#define MFMA32(a, b, c) __builtin_amdgcn_mfma_f32_32x32x16_bf16((a), (b), (c), 0, 0, 0)

// ---------------------------------------------------------------------------
// Kernel 1 (fused prep, VERIFIED R9): blocks [0,1024) build W; rest cvt x.
// ---------------------------------------------------------------------------
__global__ __launch_bounds__(256) void prep_fused(const float* __restrict__ factors,
                                                  const float* __restrict__ cores,
                                                  const float4* __restrict__ xin,
                                                  ushort4* __restrict__ xb,
                                                  unsigned short* __restrict__ Wt) {
    if (blockIdx.x >= 1024) {
        int i = (blockIdx.x - 1024) * 256 + threadIdx.x;
        float4 v = xin[i];
        ushort4 o;
        o.x = f2bf(v.x); o.y = f2bf(v.y); o.z = f2bf(v.z); o.w = f2bf(v.w);
        xb[i] = o;
        return;
    }
    __shared__ unsigned short As2[256 * 40];
    __shared__ unsigned short Bs2[64 * 40];
    __shared__ unsigned short lbuf[4 * 64 * 72];
    const int tid = threadIdx.x, lane = tid & 63, w = tid >> 6;
    const int bo = blockIdx.x >> 6, bn4 = (blockIdx.x >> 2) & 15, wn = blockIdx.x & 3;

    {
        int o01 = bo * 4 + (tid >> 6), a01 = tid & 63;
        int o0 = o01 >> 3, o1 = o01 & 7, a0 = a01 >> 3, a1 = a01 & 7;
#pragma unroll
        for (int k = 0; k < 16; ++k) {
            int b = k >> 2, q = k & 3, r0 = q >> 1, r1 = q & 1;
            float v = factors[b*512 +   0 + a0*16 + o0*2 + r0]
                    * factors[b*512 + 128 + a1*16 + o1*2 + r1];
            As2[tid * 40 + k] = f2bf(v);
            As2[tid * 40 + 16 + k] = 0;
        }
    }
    {
        int o23 = bn4 * 4 + wn, o2 = o23 >> 3, o3 = o23 & 7;
#pragma unroll
        for (int rep = 0; rep < 4; ++rep) {
            int task = rep * 256 + tid;
            int n = task >> 4, k = task & 15;
            int a2 = n >> 3, a3 = n & 7;
            int b = k >> 2, q = k & 3, r0 = q >> 1, r1 = q & 1;
            float s = 0.f;
#pragma unroll
            for (int r2 = 0; r2 < 2; ++r2)
#pragma unroll
                for (int r3 = 0; r3 < 2; ++r3)
                    s += factors[b*512 + 256 + a2*16 + o2*2 + r2]
                       * factors[b*512 + 384 + a3*16 + o3*2 + r3]
                       * cores[b*16 + r3*8 + r2*4 + r1*2 + r0];
            Bs2[n * 40 + k] = f2bf(s);
            Bs2[n * 40 + 16 + k] = 0;
        }
    }
    __syncthreads();

    const int fr = lane & 15, fh = lane >> 4;
    bf16x8 af[4], bf_[4];
#pragma unroll
    for (int mf = 0; mf < 4; ++mf)
        af[mf] = *(const bf16x8*)&As2[(w * 64 + mf * 16 + fr) * 40 + fh * 8];
#pragma unroll
    for (int nf = 0; nf < 4; ++nf)
        bf_[nf] = *(const bf16x8*)&Bs2[(nf * 16 + fr) * 40 + fh * 8];
    f32x4 acc[4][4] = {};
#pragma unroll
    for (int mf = 0; mf < 4; ++mf)
#pragma unroll
        for (int nf = 0; nf < 4; ++nf)
            acc[mf][nf] = MFMA16(af[mf], bf_[nf], acc[mf][nf]);
#pragma unroll
    for (int mf = 0; mf < 4; ++mf)
#pragma unroll
        for (int nf = 0; nf < 4; ++nf)
#pragma unroll
            for (int j = 0; j < 4; ++j)
                lbuf[w * 4608 + (mf * 16 + fh * 4 + j) * 72 + nf * 16 + fr] =
                    f2bf(acc[mf][nf][j]);
    const int o = (bo * 4 + w) * 64 + bn4 * 4 + wn;
    unsigned short* dst = Wt + (size_t)o * 4096;
#pragma unroll
    for (int i = 0; i < 8; ++i) {
        int c = i * 64 + lane;
        *(u16x8*)&dst[c * 8] =
            *(const u16x8*)&lbuf[w * 4608 + (c >> 3) * 72 + (c & 7) * 8];
    }
}

// ---------------------------------------------------------------------------
// Kernel 2: partials = A * Wt^T (per K-chunk).  v13 = R14 (32x32x16 MFMA,
// numerics verified on first call) + LGKM0 read-completion fence before every
// phase-closing barrier (fixes R14's tripwire race: next phase's glds could
// overwrite an LDS slot before a still-in-flight ds_read completed).
//   tile 128x128, BK=32, 4 waves (2x2), wave 64x64 = 2x2 of 32x32 subtiles,
//   acc[2][2] f32x16.  8 ds_read_b128 + 8 MFMA per wave-step (half of R13).
//   Staging, source-XOR swizzle, depth-2 pipeline, counted VMCNT(8/4/0),
//   split-K x2 (KCH=2048, grid 512 = 2 desync blocks/CU), XCD map: R13.
//   C/D mapping (m74/m101): col = lane&31, row = (reg&3)+8*(reg>>2)+4*hi.
// ---------------------------------------------------------------------------
__global__ __launch_bounds__(256, 2) void gemm_12832(const unsigned short* __restrict__ A,
                                                     const unsigned short* __restrict__ Bt,
                                                     float* __restrict__ P) {
    constexpr int K = 4096;
    constexpr int N = 4096;
    constexpr int BK = 32;
    constexpr int KCH = 2048;                    // 64 steps per block
    __shared__ alignas(16) char lds[3][16384];   // [buf][A 8KB | B 8KB]
    const int tid = threadIdx.x;
    const int lane = tid & 63, w = tid >> 6;
    const int wm = w >> 1, wn = w & 1;           // 2x2 waves, wave-tile 64x64
    const int xcd = blockIdx.x & 7, r = blockIdx.x >> 3;  // r 0..63
    const int bn = xcd * 4 + (r & 3);            // 0..31
    const int bm = (r >> 2) & 7;                 // 0..7
    const int ks = r >> 5;                       // 0..1

    // --- staging: A = 512 16B slots (2/thread), B = 512 (2/thread) ---
    const unsigned short* gA[2]; const unsigned short* gB[2];
    int lAoff[2], lBoff[2];
#pragma unroll
    for (int i = 0; i < 2; ++i) {
        int cs = i * 256 + tid;
        int row = cs >> 2;
        int c = (cs & 3) ^ ((row >> 1) & 3);     // source-side XOR swizzle
        gA[i] = A  + (size_t)(bm * 128 + row) * K + ks * KCH + c * 8;
        gB[i] = Bt + (size_t)(bn * 128 + row) * K + ks * KCH + c * 8;
        lAoff[i] = i * 4096 + w * 1024;          // wave-uniform base (+lane*16 HW)
        lBoff[i] = 8192 + i * 4096 + w * 1024;
    }

#define STAGE(buf, tt)                                             \
    do {                                                           \
        glds16(gA[0] + (tt) * BK, &lds[buf][lAoff[0]]);            \
        glds16(gA[1] + (tt) * BK, &lds[buf][lAoff[1]]);            \
        glds16(gB[0] + (tt) * BK, &lds[buf][lBoff[0]]);            \
        glds16(gB[1] + (tt) * BK, &lds[buf][lBoff[1]]);            \
    } while (0)

    // --- fragment read offsets (32x32 pattern, swizzled) ---
    const int lr = lane & 31, hi = lane >> 5;
    const int sk = (lr >> 1) & 3;
    int aoff[2][2], boff[2][2];                  // [kk][subtile]
#pragma unroll
    for (int kk = 0; kk < 2; ++kk)
#pragma unroll
        for (int t = 0; t < 2; ++t) {
            int ck = ((kk * 2 + hi) ^ sk) << 4;
            aoff[kk][t] = (wm * 64 + t * 32 + lr) * 64 + ck;
            boff[kk][t] = 8192 + (wn * 64 + t * 32 + lr) * 64 + ck;
        }

    f32x16 acc00 = {}, acc01 = {}, acc10 = {}, acc11 = {};

#define COMPUTE(buf)                                                          \
    do {                                                                      \
        const char* base = &lds[buf][0];                                      \
        bf16x8 a0 = *(const bf16x8*)(base + aoff[0][0]);                      \
        bf16x8 a1 = *(const bf16x8*)(base + aoff[0][1]);                      \
        bf16x8 b0 = *(const bf16x8*)(base + boff[0][0]);                      \
        bf16x8 b1 = *(const bf16x8*)(base + boff[0][1]);                      \
        bf16x8 a2 = *(const bf16x8*)(base + aoff[1][0]);                      \
        bf16x8 a3 = *(const bf16x8*)(base + aoff[1][1]);                      \
        bf16x8 b2 = *(const bf16x8*)(base + boff[1][0]);                      \
        bf16x8 b3 = *(const bf16x8*)(base + boff[1][1]);                      \
        acc00 = MFMA32(a0, b0, acc00);                                        \
        acc01 = MFMA32(a0, b1, acc01);                                        \
        acc10 = MFMA32(a1, b0, acc10);                                        \
        acc11 = MFMA32(a1, b1, acc11);                                        \
        acc00 = MFMA32(a2, b2, acc00);                                        \
        acc01 = MFMA32(a2, b3, acc01);                                        \
        acc10 = MFMA32(a3, b2, acc10);                                        \
        acc11 = MFMA32(a3, b3, acc11);                                        \
        LGKM0();  /* all ds_reads complete before the closing barrier */      \
    } while (0)

#define PHASE(tb, sbuf, cbuf)                                                 \
    do {                                                                      \
        STAGE(sbuf, (tb) + 2);                                                \
        VMCNT(8);                                                             \
        BAR();                                                                \
        COMPUTE(cbuf);                                                        \
        BAR();                                                                \
    } while (0)

    // --- depth-2 pipelined main loop: 64 steps (STAGE(s) targets buf s%3) ---
    STAGE(0, 0);
    STAGE(1, 1);
    for (int t = 0; t < 60; t += 3) {            // phases 0..59
        PHASE(t, 2, 0);
        PHASE(t + 1, 0, 1);
        PHASE(t + 2, 1, 2);
    }
    PHASE(60, 2, 0);                             // stage 62, compute 60
    PHASE(61, 0, 1);                             // stage 63, compute 61
    VMCNT(4);  BAR(); COMPUTE(2); BAR();         // compute 62
    VMCNT(0);  BAR(); COMPUTE(0);                // compute 63

    // --- epilogue: stores via verified 32x32 C/D map ---
    float* Po = P + (size_t)ks * 4194304;
    const int crow0 = bm * 128 + wm * 64 + 4 * hi;
    const int ccol0 = bn * 128 + wn * 64 + lr;
#pragma unroll
    for (int reg = 0; reg < 16; ++reg) {
        int rr = crow0 + (reg & 3) + 8 * (reg >> 2);
        Po[(size_t)(rr     ) * N + ccol0     ] = acc00[reg];
        Po[(size_t)(rr     ) * N + ccol0 + 32] = acc01[reg];
        Po[(size_t)(rr + 32) * N + ccol0     ] = acc10[reg];
        Po[(size_t)(rr + 32) * N + ccol0 + 32] = acc11[reg];
    }
#undef STAGE
#undef COMPUTE
#undef PHASE
}

// ---------------------------------------------------------------------------
// Kernel 3: C = P0 + P1 (streaming float4 reduce)
// ---------------------------------------------------------------------------
__global__ __launch_bounds__(256) void reduce2(const float4* __restrict__ P,
                                               float4* __restrict__ C) {
    int i = blockIdx.x * 256 + threadIdx.x;      // grid 4096 -> 1048576 float4
    float4 a = P[i];
    float4 b = P[i + 1048576];
    float4 o;
    o.x = a.x + b.x;
    o.y = a.y + b.y;
    o.z = a.z + b.z;
    o.w = a.w + b.w;
    C[i] = o;
}

// ---------------------------------------------------------------------------
extern "C" void kernel_launch(void* const* d_in, const int* in_sizes, int n_in,
                              void* d_out, int out_size, void* d_ws, size_t ws_size,
                              hipStream_t stream) {
    const float* inputs  = (const float*)d_in[0];   // [1024, 4096] f32
    const float* cores   = (const float*)d_in[1];   // [4, 16] f32
    const float* factors = (const float*)d_in[2];   // [4,4,8,8,2] f32
    float* out = (float*)d_out;                     // [1024, 4096] f32

    char* ws = (char*)d_ws;
    unsigned short* xb = (unsigned short*)ws;                       //  8 MB bf16 x
    unsigned short* Wt = (unsigned short*)(ws + (8u << 20));        // 32 MB bf16 W^T
    float* Pp = (float*)(ws + (40u << 20));                         // 32 MB partials

    prep_fused<<<5120, 256, 0, stream>>>(factors, cores,
                                         (const float4*)inputs, (ushort4*)xb, Wt);
    gemm_12832<<<512, 256, 0, stream>>>(xb, Wt, Pp);
    reduce2<<<4096, 256, 0, stream>>>((const float4*)Pp, (float4*)out);
}